// Round 10
// baseline (147.677 us; speedup 1.0000x reference)
//
#include <hip/hip_runtime.h>
#include <hip/hip_bf16.h>

#define B_ 2
#define P_ 100000
#define CIN_ 23
#define C_ 64
#define H_ 512
#define W_ 512
#define S_ (H_*W_)       // 262144
#define NPT_ (B_*P_)     // 200000
#define NVOX_ (B_*S_)    // 524288

typedef __attribute__((ext_vector_type(8))) short short8;
typedef __attribute__((ext_vector_type(4))) float f32x4;

__device__ inline unsigned short f2bf(float f) {
    union { __hip_bfloat16 h; unsigned short u; } cv;
    cv.h = __float2bfloat16(f);
    return cv.u;
}
__device__ inline float bf2f(unsigned short u) {
    union { unsigned int i; float f; } cv;
    cv.i = ((unsigned int)u) << 16;
    return cv.f;
}

// ---------------- Stage 1: build per-voxel linked lists ----------------
__global__ __launch_bounds__(256) void k_fill(
    const int* __restrict__ indices,
    const int* __restrict__ paddings,
    int* __restrict__ head,
    int* __restrict__ next)
{
    int pt = blockIdx.x * 256 + threadIdx.x;
    if (pt >= NPT_) return;
    if (paddings[pt] != 0) return;              // padded -> dropped
    int v = (pt / P_) * S_ + indices[pt];
    int old = atomicExch(&head[v], pt);
    next[pt] = old;
}

// ---------------- Stage 2: z = feat @ w_pn via MFMA (M=NPT_, K=23->32, N=64) -----
// one wave = 16 points; A/B/C lane mappings identical to the verified k_conv ones
__global__ __launch_bounds__(256) void k_z(
    const float* __restrict__ feat,
    const float* __restrict__ w_pn,             // [CIN_][C_] f32
    unsigned short* __restrict__ z)             // bf16 [NPT_][C_]
{
    int lane = threadIdx.x & 63;
    int wid  = (blockIdx.x * 256 + threadIdx.x) >> 6;
    int p0   = wid * 16;                        // NPT_ % 16 == 0
    int row  = lane & 15;
    int grp  = lane >> 4;

    // A fragment: A[row][k = grp*8 + j] = feat[p0+row][k], zero-pad k >= 23
    const float* f = feat + (size_t)(p0 + row) * CIN_;
    short8 a;
    #pragma unroll
    for (int j = 0; j < 8; ++j) {
        int k = grp * 8 + j;
        a[j] = (short)f2bf(k < CIN_ ? f[k] : 0.f);
    }

    // B fragments: B[k][n = t*16 + row] = w_pn[k][n], zero-pad k >= 23
    short8 bfrag[4];
    #pragma unroll
    for (int t = 0; t < 4; ++t) {
        int n = t * 16 + row;
        #pragma unroll
        for (int j = 0; j < 8; ++j) {
            int k = grp * 8 + j;
            bfrag[t][j] = (short)f2bf(k < CIN_ ? w_pn[k * C_ + n] : 0.f);
        }
    }

    f32x4 acc[4];
    #pragma unroll
    for (int t = 0; t < 4; ++t) acc[t] = (f32x4){0.f, 0.f, 0.f, 0.f};
    #pragma unroll
    for (int t = 0; t < 4; ++t)
        acc[t] = __builtin_amdgcn_mfma_f32_16x16x32_bf16(a, bfrag[t], acc[t], 0, 0, 0);

    // C[m = grp*4+r][n = t*16+row] -> z[p0+m][n]
    #pragma unroll
    for (int t = 0; t < 4; ++t)
        #pragma unroll
        for (int r = 0; r < 4; ++r)
            z[(size_t)(p0 + grp * 4 + r) * C_ + t * 16 + row] = f2bf(acc[t][r]);
}

// ---------------- Stage 3: FUSED segment-max + BN1 + 1x1conv + BN2 + ReLU --------
// one wave = 16 voxels: 16 clamped chain walks (z[0] = hot dummy for dead chains,
// all loads issue before any wait) -> swizzled per-wave LDS tile -> MFMA -> grid
__global__ __launch_bounds__(256) void k_segconv(
    const unsigned short* __restrict__ z,
    const int* __restrict__ head,
    const int* __restrict__ next,
    const float* __restrict__ g1, const float* __restrict__ b1,
    const float* __restrict__ m1, const float* __restrict__ v1,
    const float* __restrict__ conv_w,           // [out n][in k] f32
    const float* __restrict__ g2, const float* __restrict__ b2,
    const float* __restrict__ m2, const float* __restrict__ v2,
    unsigned short* __restrict__ grid)          // bf16 [NVOX_][C_] final
{
    __shared__ unsigned short lds[4][16][64];   // per-wave 16x64 bf16 tile

    int lane = threadIdx.x & 63;
    int wv   = threadIdx.x >> 6;
    int v0   = (blockIdx.x * 4 + wv) * 16;      // 8192 blocks x 4 waves x 16 = NVOX_

    // ---- phase 1: 16 independent chain walks ----
    int pc[16];
    #pragma unroll
    for (int i = 0; i < 16; ++i)
        pc[i] = __builtin_amdgcn_readfirstlane(head[v0 + i]);

    float mx[16];
    #pragma unroll
    for (int i = 0; i < 16; ++i) mx[i] = -1e30f;

    bool any = false;
    #pragma unroll
    for (int i = 0; i < 16; ++i) any |= (pc[i] >= 0);

    while (any) {
        float zz[16];
        int   nx[16];
        #pragma unroll
        for (int i = 0; i < 16; ++i) {
            int p = pc[i] < 0 ? 0 : pc[i];      // clamp: dead chains hit hot z[0]
            zz[i] = bf2f(z[(size_t)p * C_ + lane]);
            nx[i] = __builtin_amdgcn_readfirstlane(next[p]);
        }
        #pragma unroll
        for (int i = 0; i < 16; ++i) {
            if (pc[i] >= 0) mx[i] = fmaxf(mx[i], zz[i]);
            pc[i] = pc[i] < 0 ? -1 : nx[i];
        }
        any = false;
        #pragma unroll
        for (int i = 0; i < 16; ++i) any |= (pc[i] >= 0);
    }

    // ---- BN1 + ReLU -> swizzled LDS (empty voxel -> exact 0) ----
    float s1   = g1[lane] * rsqrtf(v1[lane] + 1e-5f);
    float off1 = b1[lane] - m1[lane] * s1;
    #pragma unroll
    for (int i = 0; i < 16; ++i)
        lds[wv][i][lane ^ ((i & 7) << 3)] = f2bf(fmaxf(mx[i] * s1 + off1, 0.f));

    __syncthreads();

    // ---- phase 2: 1x1 conv via MFMA ----
    int row = lane & 15;
    int grp = lane >> 4;

    short8 bfrag[4][2];
    #pragma unroll
    for (int t = 0; t < 4; ++t)
        #pragma unroll
        for (int ks = 0; ks < 2; ++ks) {
            const float* wp = conv_w + (t * 16 + row) * 64 + ks * 32 + grp * 8;
            f32x4 lo = *(const f32x4*)(wp);
            f32x4 hi = *(const f32x4*)(wp + 4);
            short8 vv;
            #pragma unroll
            for (int j = 0; j < 4; ++j) {
                vv[j]     = (short)f2bf(lo[j]);
                vv[j + 4] = (short)f2bf(hi[j]);
            }
            bfrag[t][ks] = vv;
        }

    float sc[4], sh[4];
    #pragma unroll
    for (int t = 0; t < 4; ++t) {
        int n   = t * 16 + row;
        float s = g2[n] * rsqrtf(v2[n] + 1e-3f);
        sc[t] = s;
        sh[t] = b2[n] - m2[n] * s;
    }

    // A fragments from swizzled LDS (8-short chunks stay contiguous under XOR)
    short8 a[2];
    #pragma unroll
    for (int ks = 0; ks < 2; ++ks)
        a[ks] = *(const short8*)&lds[wv][row][(ks * 32 + grp * 8) ^ ((row & 7) << 3)];

    f32x4 acc[4];
    #pragma unroll
    for (int t = 0; t < 4; ++t) acc[t] = (f32x4){0.f, 0.f, 0.f, 0.f};
    #pragma unroll
    for (int t = 0; t < 4; ++t) {
        acc[t] = __builtin_amdgcn_mfma_f32_16x16x32_bf16(a[0], bfrag[t][0], acc[t], 0, 0, 0);
        acc[t] = __builtin_amdgcn_mfma_f32_16x16x32_bf16(a[1], bfrag[t][1], acc[t], 0, 0, 0);
    }

    // epilogue: C[m = grp*4+r][n = t*16+row] -> grid[v0+m]
    #pragma unroll
    for (int r = 0; r < 4; ++r) {
        unsigned short* op = grid + (size_t)(v0 + grp * 4 + r) * C_;
        #pragma unroll
        for (int t = 0; t < 4; ++t) {
            float val = fmaxf(acc[t][r] * sc[t] + sh[t], 0.f);
            op[t * 16 + row] = f2bf(val);
        }
    }
}

// ---------------- Stage 4: bilinear gather, 4 points per wave ----------------
// im[b,x,y] = v[b,y,x] -> voxel id = y*W + x ; lane = channel
__global__ __launch_bounds__(256) void k_gather4(
    const unsigned short* __restrict__ grid,   // bf16, dense final values
    const float* __restrict__ vxyz,
    float* __restrict__ out)                   // f32 output
{
    int lane = threadIdx.x & 63;
    int gw   = (blockIdx.x * 256 + threadIdx.x) >> 6;
    int p0   = gw * 4;                          // NPT_ % 4 == 0
    if (p0 >= NPT_) return;

    #pragma unroll
    for (int k = 0; k < 4; ++k) {
        int pt = p0 + k;
        int b  = pt / P_;
        float xq = vxyz[(size_t)pt * 3 + 0];
        float yq = vxyz[(size_t)pt * 3 + 1];
        int x0 = (int)floorf(xq); x0 = min(max(x0, 0), W_ - 1);
        int x1 = min(x0 + 1, W_ - 1);
        int y0 = (int)floorf(yq); y0 = min(max(y0, 0), H_ - 1);
        int y1 = min(y0 + 1, H_ - 1);
        float x0f = (float)x0, x1f = (float)x1, y0f = (float)y0, y1f = (float)y1;
        float wa = (x1f - xq) * (y1f - yq);
        float wb = (x1f - xq) * (yq - y0f);
        float wc = (xq - x0f) * (y1f - yq);
        float wd = (xq - x0f) * (yq - y0f);

        const unsigned short* g = grid + (size_t)b * S_ * C_;
        float Ia = bf2f(g[(size_t)(y0 * W_ + x0) * C_ + lane]);
        float Ib = bf2f(g[(size_t)(y1 * W_ + x0) * C_ + lane]);
        float Ic = bf2f(g[(size_t)(y0 * W_ + x1) * C_ + lane]);
        float Id = bf2f(g[(size_t)(y1 * W_ + x1) * C_ + lane]);

        out[(size_t)pt * C_ + lane] = wa * Ia + wb * Ib + wc * Ic + wd * Id;
    }
}

extern "C" void kernel_launch(void* const* d_in, const int* in_sizes, int n_in,
                              void* d_out, int out_size, void* d_ws, size_t ws_size,
                              hipStream_t stream)
{
    const float* feat     = (const float*)d_in[1];
    const int*   indices  = (const int*)d_in[3];
    const int*   paddings = (const int*)d_in[4];
    const float* vxyz     = (const float*)d_in[5];
    const float* w_pn     = (const float*)d_in[6];
    const float* g1       = (const float*)d_in[7];
    const float* b1       = (const float*)d_in[8];
    const float* m1       = (const float*)d_in[9];
    const float* v1       = (const float*)d_in[10];
    const float* cw       = (const float*)d_in[11];
    const float* g2       = (const float*)d_in[12];
    const float* b2       = (const float*)d_in[13];
    const float* m2       = (const float*)d_in[14];
    const float* v2       = (const float*)d_in[15];

    // ws layout: grid bf16 67.1MB | z bf16 25.6MB | head 2.1MB | next 0.8MB
    char* p = (char*)d_ws;
    unsigned short* grid = (unsigned short*)p;  p += (size_t)NVOX_ * C_ * 2;
    unsigned short* z    = (unsigned short*)p;  p += (size_t)NPT_ * C_ * 2;
    int* head = (int*)p;  p += (size_t)NVOX_ * 4;
    int* next = (int*)p;

    hipMemsetAsync(head, 0xFF, (size_t)NVOX_ * 4, stream);   // head = -1

    k_fill<<<(NPT_ + 255) / 256, 256, 0, stream>>>(indices, paddings, head, next);

    // 12500 waves -> 3125 blocks
    k_z<<<3125, 256, 0, stream>>>(feat, w_pn, z);

    // NVOX_/16 = 32768 waves -> 8192 blocks
    k_segconv<<<8192, 256, 0, stream>>>(
        z, head, next, g1, b1, m1, v1, cw, g2, b2, m2, v2, grid);

    // 50000 waves -> 12500 blocks
    k_gather4<<<12500, 256, 0, stream>>>(grid, vxyz, (float*)d_out);
}

// Round 11
// 103.977 us; speedup vs baseline: 1.4203x; 1.4203x over previous
//
#include <hip/hip_runtime.h>
#include <hip/hip_bf16.h>

#define B_ 2
#define P_ 100000
#define CIN_ 23
#define C_ 64
#define H_ 512
#define W_ 512
#define S_ (H_*W_)       // 262144
#define NPT_ (B_*P_)     // 200000
#define NVOX_ (B_*S_)    // 524288

typedef __attribute__((ext_vector_type(8))) short short8;
typedef __attribute__((ext_vector_type(4))) float f32x4;
typedef __attribute__((ext_vector_type(4))) int i32x4;

__device__ inline unsigned short f2bf(float f) {
    union { __hip_bfloat16 h; unsigned short u; } cv;
    cv.h = __float2bfloat16(f);
    return cv.u;
}
__device__ inline float bf2f(unsigned short u) {
    union { unsigned int i; float f; } cv;
    cv.i = ((unsigned int)u) << 16;
    return cv.f;
}

// ---------------- Stage 1: histogram ----------------
__global__ __launch_bounds__(256) void k_hist(
    const int* __restrict__ indices,
    const int* __restrict__ paddings,
    int* __restrict__ cnt)
{
    int pt = blockIdx.x * 256 + threadIdx.x;
    if (pt >= NPT_) return;
    if (paddings[pt] != 0) return;
    int v = (pt / P_) * S_ + indices[pt];
    atomicAdd(&cnt[v], 1);
}

// ---------------- Stage 2: exclusive-scan offsets + (block 512) param prep ----------
__global__ __launch_bounds__(256) void k_offsets(
    const int* __restrict__ cnt,
    int* __restrict__ off,
    int* __restrict__ cur,
    int* __restrict__ gcursor,
    // prep inputs
    const float* __restrict__ conv_w,
    const float* __restrict__ w_pn,
    const float* __restrict__ g1, const float* __restrict__ b1,
    const float* __restrict__ m1, const float* __restrict__ v1,
    const float* __restrict__ g2, const float* __restrict__ b2,
    const float* __restrict__ m2, const float* __restrict__ v2,
    // prep outputs
    unsigned short* __restrict__ cwb,   // [8][64][8] bf16 conv-W fragments
    unsigned short* __restrict__ wpb,   // [4][64][8] bf16 w_pn fragments
    float* __restrict__ s1v, float* __restrict__ o1v,
    float* __restrict__ scv, float* __restrict__ shv)
{
    if (blockIdx.x >= 512) {            // ---- prep block ----
        int t = threadIdx.x;
        if (t < 64) {
            float s = g1[t] * rsqrtf(v1[t] + 1e-5f);
            s1v[t] = s;
            o1v[t] = b1[t] - m1[t] * s;
            float s2 = g2[t] * rsqrtf(v2[t] + 1e-3f);
            scv[t] = s2;
            shv[t] = b2[t] - m2[t] * s2;
        }
        // cwb: idx -> frag f = tq*2+ks, lane, j ; val = conv_w[(tq*16+row)*64 + ks*32+grp*8+j]
        #pragma unroll
        for (int e = 0; e < 16; ++e) {
            int idx  = t * 16 + e;              // 0..4095
            int f    = idx >> 9;                // 0..7
            int lane = (idx >> 3) & 63;
            int j    = idx & 7;
            int tq = f >> 1, ks = f & 1;
            int row = lane & 15, grp = lane >> 4;
            cwb[idx] = f2bf(conv_w[(tq * 16 + row) * 64 + ks * 32 + grp * 8 + j]);
        }
        // wpb: idx -> frag tq, lane, j ; val = w_pn[k][n], k=grp*8+j (0 for k>=23)
        #pragma unroll
        for (int e = 0; e < 8; ++e) {
            int idx  = t * 8 + e;               // 0..2047
            int tq   = idx >> 9;                // 0..3
            int lane = (idx >> 3) & 63;
            int j    = idx & 7;
            int row = lane & 15, grp = lane >> 4;
            int n = tq * 16 + row;
            int k = grp * 8 + j;
            wpb[idx] = (k < CIN_) ? f2bf(w_pn[k * C_ + n]) : 0;
        }
        return;
    }

    __shared__ int lds[256];
    __shared__ int sbase;
    int tid  = threadIdx.x;
    int base = blockIdx.x * 1024 + tid * 4;
    i32x4 c = *(const i32x4*)(cnt + base);
    int s1 = c[0] + c[1], s2 = s1 + c[2], s3 = s2 + c[3];
    lds[tid] = s3;
    __syncthreads();
    #pragma unroll
    for (int d = 1; d < 256; d <<= 1) {
        int v = (tid >= d) ? lds[tid - d] : 0;
        __syncthreads();
        if (tid >= d) lds[tid] += v;
        __syncthreads();
    }
    if (tid == 0) sbase = atomicAdd(gcursor, lds[255]);
    __syncthreads();
    int o = sbase + (tid == 0 ? 0 : lds[tid - 1]);
    i32x4 e;
    e[0] = o; e[1] = o + c[0]; e[2] = o + s1; e[3] = o + s2;
    *(i32x4*)(off + base) = e;
    *(i32x4*)(cur + base) = e;
}

// ---------------- Stage 3: z = feat @ w_pn via MFMA, scattered to voxel-sorted zs ----
// one wave = 16 points; lanes 0-15 claim slots via atomicAdd(cur[v]); C rows -> zs[slot]
__global__ __launch_bounds__(256) void k_z(
    const float* __restrict__ feat,
    const int* __restrict__ indices,
    const int* __restrict__ paddings,
    const unsigned short* __restrict__ wpb,   // [4][64][8]
    int* __restrict__ cur,
    unsigned short* __restrict__ zs)          // bf16 [NPT_][C_] voxel-sorted
{
    int lane = threadIdx.x & 63;
    int wid  = (blockIdx.x * 256 + threadIdx.x) >> 6;
    int p0   = wid * 16;                      // NPT_ % 16 == 0
    int row  = lane & 15;
    int grp  = lane >> 4;

    // slot for point p0+m, owned by lane m (m<16); padded -> -1 (dropped)
    int slot = -1;
    if (lane < 16) {
        int pt = p0 + lane;
        if (paddings[pt] == 0) {
            int v = (pt / P_) * S_ + indices[pt];
            slot = atomicAdd(&cur[v], 1);
        }
    }

    // A fragment: A[row][k = grp*8+j] = feat[p0+row][k], zero-pad k >= 23
    const float* f = feat + (size_t)(p0 + row) * CIN_;
    short8 a;
    #pragma unroll
    for (int j = 0; j < 8; ++j) {
        int k = grp * 8 + j;
        a[j] = (short)(k < CIN_ ? f2bf(f[k]) : 0);
    }

    short8 bfrag[4];
    #pragma unroll
    for (int t = 0; t < 4; ++t)
        bfrag[t] = *(const short8*)(wpb + ((size_t)t * 64 + lane) * 8);

    f32x4 acc[4];
    #pragma unroll
    for (int t = 0; t < 4; ++t) acc[t] = (f32x4){0.f, 0.f, 0.f, 0.f};
    #pragma unroll
    for (int t = 0; t < 4; ++t)
        acc[t] = __builtin_amdgcn_mfma_f32_16x16x32_bf16(a, bfrag[t], acc[t], 0, 0, 0);

    // C[m = grp*4+r][n = t*16+row] -> zs[slot_m][n]
    #pragma unroll
    for (int r = 0; r < 4; ++r) {
        int sm = __shfl(slot, grp * 4 + r);
        if (sm >= 0) {
            unsigned short* op = zs + (size_t)sm * C_;
            #pragma unroll
            for (int t = 0; t < 4; ++t)
                op[t * 16 + row] = f2bf(acc[t][r]);
        }
    }
}

// ---------------- Stage 4: FUSED reduce-max + BN1 + ReLU + 1x1conv + BN2 + ReLU ----
// one wave = 16 voxels; lane (m=lane&15, grp=lane>>4) reduces channels
// ks*32+grp*8+j of voxel v0+m directly in MFMA A-fragment layout. No LDS/barrier.
__global__ __launch_bounds__(256) void k_redconv(
    const unsigned short* __restrict__ zs,
    const int* __restrict__ cnt,
    const int* __restrict__ off,
    const float* __restrict__ s1v, const float* __restrict__ o1v,
    const unsigned short* __restrict__ cwb,   // [8][64][8]
    const float* __restrict__ scv, const float* __restrict__ shv,
    unsigned short* __restrict__ grid)        // bf16 [NVOX_][C_] final
{
    int lane = threadIdx.x & 63;
    int wid  = (blockIdx.x * 256 + threadIdx.x) >> 6;
    int v0   = wid * 16;                      // NVOX_/16 waves exactly
    int m    = lane & 15;
    int grp  = lane >> 4;

    int vi = v0 + m;
    int ci = cnt[vi];
    int oi = off[vi];

    float mx[16];
    #pragma unroll
    for (int i = 0; i < 16; ++i) mx[i] = -1e30f;

    for (int j = 0; ; ++j) {
        bool live = j < ci;
        if (!__any(live)) break;
        const unsigned short* zr =
            zs + (size_t)(oi + (live ? j : 0)) * C_ + grp * 8;
        short8 lo = *(const short8*)(zr);         // channels grp*8..+7
        short8 hi = *(const short8*)(zr + 32);    // channels 32+grp*8..+7
        if (live) {
            #pragma unroll
            for (int jj = 0; jj < 8; ++jj) {
                mx[jj]     = fmaxf(mx[jj],     bf2f((unsigned short)lo[jj]));
                mx[8 + jj] = fmaxf(mx[8 + jj], bf2f((unsigned short)hi[jj]));
            }
        }
    }

    // BN1 + ReLU -> A fragments (empty voxel: -1e30 -> relu -> 0 exactly)
    short8 a[2];
    #pragma unroll
    for (int jj = 0; jj < 8; ++jj) {
        int c0 = grp * 8 + jj;
        int c1 = 32 + grp * 8 + jj;
        a[0][jj] = (short)f2bf(fmaxf(mx[jj]     * s1v[c0] + o1v[c0], 0.f));
        a[1][jj] = (short)f2bf(fmaxf(mx[8 + jj] * s1v[c1] + o1v[c1], 0.f));
    }

    short8 bfrag[4][2];
    #pragma unroll
    for (int t = 0; t < 4; ++t)
        #pragma unroll
        for (int ks = 0; ks < 2; ++ks)
            bfrag[t][ks] = *(const short8*)(cwb + ((size_t)(t * 2 + ks) * 64 + lane) * 8);

    f32x4 acc[4];
    #pragma unroll
    for (int t = 0; t < 4; ++t) acc[t] = (f32x4){0.f, 0.f, 0.f, 0.f};
    #pragma unroll
    for (int t = 0; t < 4; ++t) {
        acc[t] = __builtin_amdgcn_mfma_f32_16x16x32_bf16(a[0], bfrag[t][0], acc[t], 0, 0, 0);
        acc[t] = __builtin_amdgcn_mfma_f32_16x16x32_bf16(a[1], bfrag[t][1], acc[t], 0, 0, 0);
    }

    // BN2 + ReLU epilogue: C[mr = grp*4+r][n = t*16+m] -> grid[v0+mr]
    float sc[4], sh[4];
    #pragma unroll
    for (int t = 0; t < 4; ++t) {
        int n = t * 16 + m;
        sc[t] = scv[n];
        sh[t] = shv[n];
    }
    #pragma unroll
    for (int r = 0; r < 4; ++r) {
        unsigned short* op = grid + (size_t)(v0 + grp * 4 + r) * C_;
        #pragma unroll
        for (int t = 0; t < 4; ++t) {
            float val = fmaxf(acc[t][r] * sc[t] + sh[t], 0.f);
            op[t * 16 + m] = f2bf(val);
        }
    }
}

// ---------------- Stage 5: bilinear gather, 8 points per wave ----------------
__global__ __launch_bounds__(256) void k_gather8(
    const unsigned short* __restrict__ grid,   // bf16, dense final values
    const float* __restrict__ vxyz,
    float* __restrict__ out)                   // f32 output
{
    int lane = threadIdx.x & 63;
    int gw   = (blockIdx.x * 256 + threadIdx.x) >> 6;
    int p0   = gw * 8;                          // NPT_ % 8 == 0
    if (p0 >= NPT_) return;

    #pragma unroll
    for (int k = 0; k < 8; ++k) {
        int pt = p0 + k;
        int b  = pt / P_;
        float xq = vxyz[(size_t)pt * 3 + 0];
        float yq = vxyz[(size_t)pt * 3 + 1];
        int x0 = (int)floorf(xq); x0 = min(max(x0, 0), W_ - 1);
        int x1 = min(x0 + 1, W_ - 1);
        int y0 = (int)floorf(yq); y0 = min(max(y0, 0), H_ - 1);
        int y1 = min(y0 + 1, H_ - 1);
        float x0f = (float)x0, x1f = (float)x1, y0f = (float)y0, y1f = (float)y1;
        float wa = (x1f - xq) * (y1f - yq);
        float wb = (x1f - xq) * (yq - y0f);
        float wc = (xq - x0f) * (y1f - yq);
        float wd = (xq - x0f) * (yq - y0f);

        const unsigned short* g = grid + (size_t)b * S_ * C_;
        float Ia = bf2f(g[(size_t)(y0 * W_ + x0) * C_ + lane]);
        float Ib = bf2f(g[(size_t)(y1 * W_ + x0) * C_ + lane]);
        float Ic = bf2f(g[(size_t)(y0 * W_ + x1) * C_ + lane]);
        float Id = bf2f(g[(size_t)(y1 * W_ + x1) * C_ + lane]);

        out[(size_t)pt * C_ + lane] = wa * Ia + wb * Ib + wc * Ic + wd * Id;
    }
}

extern "C" void kernel_launch(void* const* d_in, const int* in_sizes, int n_in,
                              void* d_out, int out_size, void* d_ws, size_t ws_size,
                              hipStream_t stream)
{
    const float* feat     = (const float*)d_in[1];
    const int*   indices  = (const int*)d_in[3];
    const int*   paddings = (const int*)d_in[4];
    const float* vxyz     = (const float*)d_in[5];
    const float* w_pn     = (const float*)d_in[6];
    const float* g1       = (const float*)d_in[7];
    const float* b1       = (const float*)d_in[8];
    const float* m1       = (const float*)d_in[9];
    const float* v1       = (const float*)d_in[10];
    const float* cw       = (const float*)d_in[11];
    const float* g2       = (const float*)d_in[12];
    const float* b2       = (const float*)d_in[13];
    const float* m2       = (const float*)d_in[14];
    const float* v2       = (const float*)d_in[15];

    // ws layout: grid 67.1MB | zs 25.6MB | cnt 2MB | off 2MB | cur 2MB |
    //            gcursor 16B | cwb 8KB | wpb 4KB | s1v/o1v/scv/shv 4x256B
    char* p = (char*)d_ws;
    unsigned short* grid = (unsigned short*)p;  p += (size_t)NVOX_ * C_ * 2;
    unsigned short* zs   = (unsigned short*)p;  p += (size_t)NPT_ * C_ * 2;
    int* cnt  = (int*)p;  p += (size_t)NVOX_ * 4;
    int* off  = (int*)p;  p += (size_t)NVOX_ * 4;
    int* cur  = (int*)p;  p += (size_t)NVOX_ * 4;
    int* gcur = (int*)p;  p += 16;
    unsigned short* cwb = (unsigned short*)p;  p += 8 * 64 * 8 * 2;
    unsigned short* wpb = (unsigned short*)p;  p += 4 * 64 * 8 * 2;
    float* s1v = (float*)p;  p += 64 * 4;
    float* o1v = (float*)p;  p += 64 * 4;
    float* scv = (float*)p;  p += 64 * 4;
    float* shv = (float*)p;

    hipMemsetAsync(cnt, 0, (size_t)NVOX_ * 4, stream);
    hipMemsetAsync(gcur, 0, 4, stream);

    k_hist<<<(NPT_ + 255) / 256, 256, 0, stream>>>(indices, paddings, cnt);

    // 512 scan blocks + 1 prep block
    k_offsets<<<513, 256, 0, stream>>>(cnt, off, cur, gcur,
        cw, w_pn, g1, b1, m1, v1, g2, b2, m2, v2,
        cwb, wpb, s1v, o1v, scv, shv);

    // 12500 waves -> 3125 blocks
    k_z<<<3125, 256, 0, stream>>>(feat, indices, paddings, wpb, cur, zs);

    // NVOX_/16 = 32768 waves -> 8192 blocks
    k_redconv<<<8192, 256, 0, stream>>>(zs, cnt, off, s1v, o1v, cwb, scv, shv, grid);

    // 25000 waves -> 6250 blocks
    k_gather8<<<6250, 256, 0, stream>>>(grid, vxyz, (float*)d_out);
}